// Round 4
// baseline (3264.542 us; speedup 1.0000x reference)
//
#include <hip/hip_runtime.h>
#include <hip/hip_bf16.h>

// ---------------------------------------------------------------------------
// MoE transformer block, MI355X. Round 4: f32 inputs, f32 OUTPUT (reference
// returns float32; "bf16" in the harness label is cosmetic). y accumulates
// directly in d_out. fp32 internal math throughout.
//   ws region A [0, 2.10M floats):  xnorm -> attn_out
//   ws region R1 [2.10M, 8.39M):    qkv -> h_pairs -> hs
//   x_ffn_in [8.39M, 10.49M) ; x_ffn [10.49M, 12.58M) ; sc/ints after (~50MB)
// ---------------------------------------------------------------------------

#define S_LEN   1024
#define T_TOT   2048
#define DMODEL  1024
#define NHEADS  16
#define HDIM    64
#define NEXP    16
#define FDIM    512
#define DSH     2048
#define TOPK    4
#define NPAIR   8192

__device__ __forceinline__ float sigm(float x) { return 1.0f / (1.0f + __expf(-x)); }

// ---------------- RMSNorm (f32 in, f32 out) ----------------
__global__ void rmsnorm_kernel(const float* __restrict__ x,
                               const float* __restrict__ w,
                               float* __restrict__ out) {
    int t = blockIdx.x, tid = threadIdx.x;
    float4 xv = *(const float4*)(x + (size_t)t * DMODEL + tid * 4);
    __shared__ float rb[256];
    rb[tid] = xv.x*xv.x + xv.y*xv.y + xv.z*xv.z + xv.w*xv.w;
    __syncthreads();
    for (int s = 128; s > 0; s >>= 1) { if (tid < s) rb[tid] += rb[tid+s]; __syncthreads(); }
    float scale = rsqrtf(rb[0] * (1.0f/1024.0f) + 1e-5f);
    float4 wv = *(const float4*)(w + tid * 4);
    float4 o;
    o.x = xv.x * scale * wv.x;
    o.y = xv.y * scale * wv.y;
    o.z = xv.z * scale * wv.z;
    o.w = xv.w * scale * wv.w;
    *(float4*)(out + (size_t)t*DMODEL + tid*4) = o;
}

// ---------------- generic tiled GEMM: C[M,N] = A[M,K] @ B[K,N] (all f32) ----
// MODE 0: overwrite; 1: C += ; 2: C = A@B + residual
template<int MODE>
__global__ __launch_bounds__(256) void gemm_kernel(
        const float* __restrict__ A, const float* __restrict__ B,
        float* __restrict__ C, const float* __restrict__ resid,
        int M, int N, int Kd) {
    __shared__ float As[16][68];
    __shared__ float Bs[16][68];
    int tid = threadIdx.x;
    int m0 = blockIdx.y * 64, n0 = blockIdx.x * 64;
    int ty = tid >> 4, tx = tid & 15;
    int arow = tid >> 2, acol = (tid & 3) << 2;
    int brow = tid >> 4, bcol = (tid & 15) << 2;
    float acc[4][4] = {};
    for (int k0 = 0; k0 < Kd; k0 += 16) {
        __syncthreads();
        float4 av = *(const float4*)(A + (size_t)(m0 + arow) * Kd + k0 + acol);
        As[acol+0][arow] = av.x; As[acol+1][arow] = av.y;
        As[acol+2][arow] = av.z; As[acol+3][arow] = av.w;
        float4 bv = *(const float4*)(B + (size_t)(k0 + brow) * N + n0 + bcol);
        Bs[brow][bcol+0] = bv.x; Bs[brow][bcol+1] = bv.y;
        Bs[brow][bcol+2] = bv.z; Bs[brow][bcol+3] = bv.w;
        __syncthreads();
        #pragma unroll
        for (int k = 0; k < 16; ++k) {
            float4 a = *(const float4*)&As[k][ty << 2];
            float4 b = *(const float4*)&Bs[k][tx << 2];
            float avv[4] = {a.x, a.y, a.z, a.w};
            float bvv[4] = {b.x, b.y, b.z, b.w};
            #pragma unroll
            for (int i = 0; i < 4; ++i)
                #pragma unroll
                for (int j = 0; j < 4; ++j)
                    acc[i][j] += avv[i] * bvv[j];
        }
    }
    #pragma unroll
    for (int i = 0; i < 4; ++i) {
        size_t off = (size_t)(m0 + (ty << 2) + i) * N + n0 + (tx << 2);
        float4 v = make_float4(acc[i][0], acc[i][1], acc[i][2], acc[i][3]);
        if (MODE == 1) {
            float4 c0 = *(const float4*)(C + off);
            v.x += c0.x; v.y += c0.y; v.z += c0.z; v.w += c0.w;
        } else if (MODE == 2) {
            float4 rv = *(const float4*)(resid + off);
            v.x += rv.x; v.y += rv.y; v.z += rv.z; v.w += rv.w;
        }
        *(float4*)(C + off) = v;
    }
}

// ---------------- RoPE, in-place on qkv rows (q and k only) ----------------
__global__ void rope_kernel(float* __restrict__ qkv) {
    int t = blockIdx.x, tid = threadIdx.x;
    int s = t & 1023;                 // position within half-sequence
    float* row = qkv + (size_t)t * 3072;
    for (int pp = tid; pp < 512; pp += 256) {
        int h = pp >> 5, i = pp & 31;
        float fr = (float)s * exp2f(-0.41524101186092028f * (float)i);
        float sn, cs;
        sincosf(fr, &sn, &cs);
        int o1 = (h << 6) + i, o2 = o1 + 32;
        float x1 = row[o1], x2 = row[o2];
        row[o1] = x1 * cs + x2 * sn;
        row[o2] = x2 * cs - x1 * sn;
        x1 = row[1024 + o1]; x2 = row[1024 + o2];
        row[1024 + o1] = x1 * cs + x2 * sn;
        row[1024 + o2] = x2 * cs - x1 * sn;
    }
}

// ---------------- flash attention (causal, online softmax) ----------------
// Reads q/k/v straight from qkv rows; interleaved position p -> token
// t = (p&1)*1024 + (p>>1).  attn_out: [token][1024] f32.
__global__ __launch_bounds__(256) void attn_kernel(
        const float* __restrict__ qkv, float* __restrict__ attn_out) {
    int qt = blockIdx.x, h = blockIdx.y;
    __shared__ float Qs[64][68], Ks[64][68], Vs[64][68];
    int tid = threadIdx.x;
    int r = tid >> 2, qd = tid & 3;
    int lane = tid & 63, gbase = lane & ~3;
    for (int idx = tid * 4; idx < 4096; idx += 1024) {
        int rr = idx >> 6, cc = idx & 63;
        int p = qt * 64 + rr;
        int t = ((p & 1) << 10) + (p >> 1);
        *(float4*)&Qs[rr][cc] = *(const float4*)(qkv + (size_t)t * 3072 + (h << 6) + cc);
    }
    float m = -1e30f, l = 0.0f;
    float acc[16];
    #pragma unroll
    for (int a = 0; a < 16; ++a) acc[a] = 0.0f;
    int pq = qt * 64 + r;
    int j0 = qd << 4;
    for (int kb = 0; kb <= qt; ++kb) {
        __syncthreads();
        for (int idx = tid * 4; idx < 4096; idx += 1024) {
            int rr = idx >> 6, cc = idx & 63;
            int p = kb * 64 + rr;
            int t = ((p & 1) << 10) + (p >> 1);
            const float* base = qkv + (size_t)t * 3072 + (h << 6) + cc;
            *(float4*)&Ks[rr][cc] = *(const float4*)(base + 1024);
            *(float4*)&Vs[rr][cc] = *(const float4*)(base + 2048);
        }
        __syncthreads();
        float sv[16];
        #pragma unroll
        for (int jj = 0; jj < 16; ++jj) sv[jj] = 0.0f;
        for (int a = 0; a < 64; a += 4) {
            float4 qa = *(const float4*)&Qs[r][a];
            #pragma unroll
            for (int jj = 0; jj < 16; ++jj) {
                float4 ka = *(const float4*)&Ks[j0 + jj][a];
                sv[jj] += qa.x*ka.x + qa.y*ka.y + qa.z*ka.z + qa.w*ka.w;
            }
        }
        float mloc = -1e30f;
        #pragma unroll
        for (int jj = 0; jj < 16; ++jj) {
            float v = sv[jj] * 0.125f;
            if (kb == qt && (j0 + jj) > r) v = -1e30f;   // causal (diag tile)
            sv[jj] = v;
            mloc = fmaxf(mloc, v);
        }
        mloc = fmaxf(mloc, __shfl_xor(mloc, 1));
        mloc = fmaxf(mloc, __shfl_xor(mloc, 2));
        float mnew = fmaxf(m, mloc);
        float alpha = __expf(m - mnew);
        float psum = 0.0f;
        #pragma unroll
        for (int jj = 0; jj < 16; ++jj) {
            float pv = __expf(sv[jj] - mnew);
            sv[jj] = pv; psum += pv;
        }
        psum += __shfl_xor(psum, 1);
        psum += __shfl_xor(psum, 2);
        l = l * alpha + psum;
        m = mnew;
        #pragma unroll
        for (int a = 0; a < 16; ++a) acc[a] *= alpha;
        #pragma unroll
        for (int g = 0; g < 4; ++g) {
            #pragma unroll
            for (int jj = 0; jj < 16; ++jj) {
                float pv = __shfl(sv[jj], gbase + g);
                const float* vrow = &Vs[g * 16 + jj][j0];
                float4 v0 = *(const float4*)(vrow);
                float4 v1 = *(const float4*)(vrow + 4);
                float4 v2 = *(const float4*)(vrow + 8);
                float4 v3 = *(const float4*)(vrow + 12);
                acc[0]  += pv*v0.x; acc[1]  += pv*v0.y; acc[2]  += pv*v0.z; acc[3]  += pv*v0.w;
                acc[4]  += pv*v1.x; acc[5]  += pv*v1.y; acc[6]  += pv*v1.z; acc[7]  += pv*v1.w;
                acc[8]  += pv*v2.x; acc[9]  += pv*v2.y; acc[10] += pv*v2.z; acc[11] += pv*v2.w;
                acc[12] += pv*v3.x; acc[13] += pv*v3.y; acc[14] += pv*v3.z; acc[15] += pv*v3.w;
            }
        }
    }
    float invl = 1.0f / l;
    int c = pq & 1, sdx = pq >> 1;
    float* op = attn_out + ((size_t)(c * 1024 + sdx) << 10) + (h << 6) + j0;
    #pragma unroll
    for (int a4 = 0; a4 < 4; ++a4) {
        float4 o = make_float4(acc[a4*4+0]*invl, acc[a4*4+1]*invl,
                               acc[a4*4+2]*invl, acc[a4*4+3]*invl);
        *(float4*)(op + a4 * 4) = o;
    }
}

// ---------------- router ----------------
__global__ void router_kernel(const float* __restrict__ xffn,
        const float* __restrict__ p_keys, const float* __restrict__ f_keys,
        const int* __restrict__ p_idx, const int* __restrict__ f_idx,
        const float* __restrict__ p_val, const float* __restrict__ f_val,
        const float* __restrict__ p_bias, const float* __restrict__ f_bias,
        float* __restrict__ sc) {
    int tl = blockIdx.x, hf = blockIdx.y;
    int t = hf * 1024 + tl;
    const float* keys = hf ? f_keys : p_keys;
    const int* idx    = hf ? f_idx  : p_idx;
    const float* val  = hf ? f_val  : p_val;
    const float* bias = hf ? f_bias : p_bias;
    int tid = threadIdx.x;
    float acc[16];
    #pragma unroll
    for (int e = 0; e < 16; ++e) acc[e] = 0.0f;
    const float* x = xffn + (size_t)t * DMODEL;
    for (int d = tid; d < 1024; d += 256) {
        float xd = x[d];
        const float* kr = keys + d * 16;
        #pragma unroll
        for (int e4 = 0; e4 < 4; ++e4) {
            float4 kv = *(const float4*)(kr + e4 * 4);
            acc[e4*4+0] += xd * kv.x;
            acc[e4*4+1] += xd * kv.y;
            acc[e4*4+2] += xd * kv.z;
            acc[e4*4+3] += xd * kv.w;
        }
    }
    #pragma unroll
    for (int e = 0; e < 16; ++e) {
        float v = acc[e];
        v += __shfl_down(v, 32); v += __shfl_down(v, 16); v += __shfl_down(v, 8);
        v += __shfl_down(v, 4);  v += __shfl_down(v, 2);  v += __shfl_down(v, 1);
        acc[e] = v;
    }
    __shared__ float part[4][16];
    __shared__ float logit[16];
    __shared__ float sg[4];
    int wave = tid >> 6, ln = tid & 63;
    if (ln == 0) {
        #pragma unroll
        for (int e = 0; e < 16; ++e) part[wave][e] = acc[e];
    }
    __syncthreads();
    if (tid < 16) logit[tid] = part[0][tid] + part[1][tid] + part[2][tid] + part[3][tid];
    __syncthreads();
    if (tid < 4) {
        int ii = idx[tl * 4 + tid];
        float v = val[tl * 4 + tid] + logit[ii] + bias[ii];
        sg[tid] = 1.0f / (1.0f + expf(-v));
    }
    __syncthreads();
    if (tid < 4) {
        float ssum = sg[0] + sg[1] + sg[2] + sg[3];
        sc[t * 4 + tid] = sg[tid] / ssum;
    }
}

// ---------------- expert bucketing (single workgroup) ----------------
// pair id p = hf*4096 + tl*4 + k  (== flat index into sc).
__global__ __launch_bounds__(1024) void buckets_kernel(
        const int* __restrict__ p_idx, const int* __restrict__ f_idx,
        int* __restrict__ counts, int* __restrict__ offsets,
        int* __restrict__ pair_p) {
    __shared__ int lcnt[32], loff[32], lcur[32];
    int tid = threadIdx.x;
    if (tid < 32) { lcnt[tid] = 0; lcur[tid] = 0; }
    __syncthreads();
    for (int p = tid; p < NPAIR; p += 1024) {
        int hf = p >> 12, rem = p & 4095;
        int e = (hf ? f_idx : p_idx)[rem];
        atomicAdd(&lcnt[(hf << 4) + e], 1);
    }
    __syncthreads();
    if (tid == 0) {
        int o = 0;
        for (int b = 0; b < 32; ++b) { loff[b] = o; o += lcnt[b]; }
    }
    __syncthreads();
    for (int p = tid; p < NPAIR; p += 1024) {
        int hf = p >> 12, rem = p & 4095;
        int e = (hf ? f_idx : p_idx)[rem];
        int b = (hf << 4) + e;
        int pos = atomicAdd(&lcur[b], 1);
        pair_p[loff[b] + pos] = p;
    }
    if (tid < 32) { counts[tid] = lcnt[tid]; offsets[tid] = loff[tid]; }
}

__device__ __forceinline__ int pair2tok(int p) {
    return ((p >> 12) << 10) + ((p & 4095) >> 2);
}

// ---------------- MoE gate+up (gather GEMM, silu fused) ----------------
__global__ __launch_bounds__(256) void moe_gateup_kernel(
        const float* __restrict__ xffn,
        const float* __restrict__ p_experts,
        const float* __restrict__ f_experts,
        const int* __restrict__ pair_p,
        const int* __restrict__ counts, const int* __restrict__ offsets,
        float* __restrict__ h_pairs) {
    int bucket = blockIdx.y;
    int cnt = counts[bucket];
    int tile0 = blockIdx.x * 64;
    if (tile0 >= cnt) return;
    int f0 = blockIdx.z * 64;
    int e = bucket & 15;
    const float* base = (bucket >> 4) ? f_experts : p_experts;
    const float* Wg = base + (size_t)e * (DMODEL * FDIM);
    const float* Wu = base + (size_t)(NEXP + e) * (DMODEL * FDIM);
    int slot0 = offsets[bucket] + tile0;
    __shared__ int toks[64];
    __shared__ float As[16][68];
    __shared__ float Bg[16][68];
    __shared__ float Bu[16][68];
    int tid = threadIdx.x;
    if (tid < 64)
        toks[tid] = (tile0 + tid < cnt) ? pair2tok(pair_p[slot0 + tid]) : 0;
    int ty = tid >> 4, tx = tid & 15;
    int arow = tid >> 2, acol = (tid & 3) << 2;
    int brow = tid >> 4, bcol = (tid & 15) << 2;
    float ag[4][4] = {}, au[4][4] = {};
    __syncthreads();
    int tok = toks[arow];
    for (int k0 = 0; k0 < DMODEL; k0 += 16) {
        __syncthreads();
        float4 av = *(const float4*)(xffn + (size_t)tok * DMODEL + k0 + acol);
        As[acol+0][arow] = av.x; As[acol+1][arow] = av.y;
        As[acol+2][arow] = av.z; As[acol+3][arow] = av.w;
        float4 g4 = *(const float4*)(Wg + (size_t)(k0 + brow) * FDIM + f0 + bcol);
        float4 u4 = *(const float4*)(Wu + (size_t)(k0 + brow) * FDIM + f0 + bcol);
        Bg[brow][bcol+0] = g4.x; Bg[brow][bcol+1] = g4.y;
        Bg[brow][bcol+2] = g4.z; Bg[brow][bcol+3] = g4.w;
        Bu[brow][bcol+0] = u4.x; Bu[brow][bcol+1] = u4.y;
        Bu[brow][bcol+2] = u4.z; Bu[brow][bcol+3] = u4.w;
        __syncthreads();
        #pragma unroll
        for (int k = 0; k < 16; ++k) {
            float4 a  = *(const float4*)&As[k][ty << 2];
            float4 bg = *(const float4*)&Bg[k][tx << 2];
            float4 bu = *(const float4*)&Bu[k][tx << 2];
            float avv[4] = {a.x, a.y, a.z, a.w};
            float bgv[4] = {bg.x, bg.y, bg.z, bg.w};
            float buv[4] = {bu.x, bu.y, bu.z, bu.w};
            #pragma unroll
            for (int i = 0; i < 4; ++i)
                #pragma unroll
                for (int j = 0; j < 4; ++j) {
                    ag[i][j] += avv[i] * bgv[j];
                    au[i][j] += avv[i] * buv[j];
                }
        }
    }
    #pragma unroll
    for (int i = 0; i < 4; ++i) {
        int rr = (ty << 2) + i;
        if (tile0 + rr < cnt) {
            float4 o;
            float g;
            g = ag[i][0]; o.x = g * sigm(g) * au[i][0];
            g = ag[i][1]; o.y = g * sigm(g) * au[i][1];
            g = ag[i][2]; o.z = g * sigm(g) * au[i][2];
            g = ag[i][3]; o.w = g * sigm(g) * au[i][3];
            *(float4*)(h_pairs + (size_t)(slot0 + rr) * FDIM + f0 + (tx << 2)) = o;
        }
    }
}

// ---------------- MoE down: y[token] += score * (h[slot] . Wd[e][d,:]) -----
__global__ __launch_bounds__(256) void moe_down_kernel(
        const float* __restrict__ h_pairs,
        const float* __restrict__ p_experts,
        const float* __restrict__ f_experts,
        const int* __restrict__ pair_p,
        const int* __restrict__ counts, const int* __restrict__ offsets,
        const float* __restrict__ sc,
        float* __restrict__ y) {
    int bucket = blockIdx.y;
    int cnt = counts[bucket];
    int tile0 = blockIdx.x * 64;
    if (tile0 >= cnt) return;
    int d0 = blockIdx.z * 64;
    int e = bucket & 15;
    const float* base = (bucket >> 4) ? f_experts : p_experts;
    const float* Wd = base + (size_t)(2 * NEXP + e) * (DMODEL * FDIM);
    int slot0 = offsets[bucket] + tile0;
    __shared__ float As[16][68];
    __shared__ float Bs[16][68];
    __shared__ int   tokd[64];
    __shared__ float scd[64];
    int tid = threadIdx.x;
    if (tid < 64) {
        int ok = (tile0 + tid < cnt);
        int pr = ok ? pair_p[slot0 + tid] : 0;
        tokd[tid] = pair2tok(pr);
        scd[tid]  = ok ? sc[pr] : 0.0f;
    }
    int ty = tid >> 4, tx = tid & 15;
    int arow = tid >> 2, acol = (tid & 3) << 2;
    int bn = tid >> 2, bk = (tid & 3) << 2;
    float acc[4][4] = {};
    for (int k0 = 0; k0 < FDIM; k0 += 16) {
        __syncthreads();
        float4 av = *(const float4*)(h_pairs + (size_t)(slot0 + arow) * FDIM + k0 + acol);
        As[acol+0][arow] = av.x; As[acol+1][arow] = av.y;
        As[acol+2][arow] = av.z; As[acol+3][arow] = av.w;
        float4 b4 = *(const float4*)(Wd + (size_t)(d0 + bn) * FDIM + k0 + bk);
        Bs[bk+0][bn] = b4.x; Bs[bk+1][bn] = b4.y;
        Bs[bk+2][bn] = b4.z; Bs[bk+3][bn] = b4.w;
        __syncthreads();
        #pragma unroll
        for (int k = 0; k < 16; ++k) {
            float4 a = *(const float4*)&As[k][ty << 2];
            float4 b = *(const float4*)&Bs[k][tx << 2];
            float avv[4] = {a.x, a.y, a.z, a.w};
            float bvv[4] = {b.x, b.y, b.z, b.w};
            #pragma unroll
            for (int i = 0; i < 4; ++i)
                #pragma unroll
                for (int j = 0; j < 4; ++j)
                    acc[i][j] += avv[i] * bvv[j];
        }
    }
    #pragma unroll
    for (int i = 0; i < 4; ++i) {
        int rr = (ty << 2) + i;
        if (tile0 + rr < cnt) {
            int   t = tokd[rr];
            float s = scd[rr];
            float* yp = y + (size_t)t * DMODEL + d0 + (tx << 2);
            atomicAdd(yp + 0, s * acc[i][0]);
            atomicAdd(yp + 1, s * acc[i][1]);
            atomicAdd(yp + 2, s * acc[i][2]);
            atomicAdd(yp + 3, s * acc[i][3]);
        }
    }
}

// ---------------- shared expert gate+up fused (silu(g)*u -> hs) ------------
__global__ __launch_bounds__(256) void shared_gateup_kernel(
        const float* __restrict__ x, const float* __restrict__ W1,
        float* __restrict__ hs) {
    // M=2048, half-N=2048 (g cols j, u cols 2048+j), K=1024, row stride 4096
    int m0 = blockIdx.y * 64, j0 = blockIdx.x * 64;
    __shared__ float As[16][68];
    __shared__ float Bg[16][68];
    __shared__ float Bu[16][68];
    int tid = threadIdx.x;
    int ty = tid >> 4, tx = tid & 15;
    int arow = tid >> 2, acol = (tid & 3) << 2;
    int brow = tid >> 4, bcol = (tid & 15) << 2;
    float ag[4][4] = {}, au[4][4] = {};
    for (int k0 = 0; k0 < DMODEL; k0 += 16) {
        __syncthreads();
        float4 av = *(const float4*)(x + (size_t)(m0 + arow) * DMODEL + k0 + acol);
        As[acol+0][arow] = av.x; As[acol+1][arow] = av.y;
        As[acol+2][arow] = av.z; As[acol+3][arow] = av.w;
        const float* wrow = W1 + (size_t)(k0 + brow) * (2 * DSH) + j0 + bcol;
        float4 g4 = *(const float4*)(wrow);
        float4 u4 = *(const float4*)(wrow + DSH);
        Bg[brow][bcol+0] = g4.x; Bg[brow][bcol+1] = g4.y;
        Bg[brow][bcol+2] = g4.z; Bg[brow][bcol+3] = g4.w;
        Bu[brow][bcol+0] = u4.x; Bu[brow][bcol+1] = u4.y;
        Bu[brow][bcol+2] = u4.z; Bu[brow][bcol+3] = u4.w;
        __syncthreads();
        #pragma unroll
        for (int k = 0; k < 16; ++k) {
            float4 a  = *(const float4*)&As[k][ty << 2];
            float4 bg = *(const float4*)&Bg[k][tx << 2];
            float4 bu = *(const float4*)&Bu[k][tx << 2];
            float avv[4] = {a.x, a.y, a.z, a.w};
            float bgv[4] = {bg.x, bg.y, bg.z, bg.w};
            float buv[4] = {bu.x, bu.y, bu.z, bu.w};
            #pragma unroll
            for (int i = 0; i < 4; ++i)
                #pragma unroll
                for (int j = 0; j < 4; ++j) {
                    ag[i][j] += avv[i] * bgv[j];
                    au[i][j] += avv[i] * buv[j];
                }
        }
    }
    #pragma unroll
    for (int i = 0; i < 4; ++i) {
        float4 o;
        float g;
        g = ag[i][0]; o.x = g * sigm(g) * au[i][0];
        g = ag[i][1]; o.y = g * sigm(g) * au[i][1];
        g = ag[i][2]; o.z = g * sigm(g) * au[i][2];
        g = ag[i][3]; o.w = g * sigm(g) * au[i][3];
        *(float4*)(hs + (size_t)(m0 + (ty << 2) + i) * DSH + j0 + (tx << 2)) = o;
    }
}

// ===========================================================================
extern "C" void kernel_launch(void* const* d_in, const int* in_sizes, int n_in,
                              void* d_out, int out_size, void* d_ws, size_t ws_size,
                              hipStream_t stream) {
    const float* x_input  = (const float*)d_in[0];
    const int*   p_idx    = (const int*)d_in[1];
    const float* p_val    = (const float*)d_in[2];
    const int*   f_idx    = (const int*)d_in[3];
    const float* f_val    = (const float*)d_in[4];
    const float* attn_w   = (const float*)d_in[5];
    const float* ffn_w    = (const float*)d_in[6];
    const float* W_attn   = (const float*)d_in[7];
    const float* W_attn_o = (const float*)d_in[8];
    const float* ffn_up   = (const float*)d_in[9];
    const float* ffn_down = (const float*)d_in[10];
    const float* p_exp    = (const float*)d_in[11];
    const float* f_exp    = (const float*)d_in[12];
    const float* p_keys   = (const float*)d_in[13];
    const float* f_keys   = (const float*)d_in[14];
    const float* p_bias   = (const float*)d_in[15];
    const float* f_bias   = (const float*)d_in[16];
    float* y32 = (float*)d_out;                 // OUTPUT IS F32, accumulate here
    (void)in_sizes; (void)n_in; (void)out_size; (void)ws_size;

    float* ws = (float*)d_ws;
    // region A [0, 2,097,152): xnorm -> attn_out
    float* xnorm     = ws;
    float* attn_out  = ws;
    // region R1 [2,097,152, 8,388,608): qkv -> h_pairs -> hs
    float* R1        = ws + 2097152;
    float* qkv       = R1;                      // 2048*3072 = 6,291,456
    float* h_pairs   = R1;                      // 8192*512  = 4,194,304
    float* hs        = R1;                      // 2048*2048 = 4,194,304
    float* x_ffn_in  = ws + 8388608;            // 2,097,152
    float* x_ffn     = ws + 10485760;           // 2,097,152
    float* sc        = ws + 12582912;           // 8192
    int*   counts    = (int*)(ws + 12591104);   // 32
    int*   offsets   = counts + 32;             // 32
    int*   pair_p    = offsets + 32;            // 8192   (end ~50.4 MB)

    // 1) attn-input RMSNorm
    rmsnorm_kernel<<<T_TOT, 256, 0, stream>>>(x_input, attn_w, xnorm);
    // 2) QKV projection
    gemm_kernel<0><<<dim3(48, 32), 256, 0, stream>>>(xnorm, W_attn, qkv, nullptr,
                                                     T_TOT, 3072, 1024);
    // 3) RoPE in-place on q,k
    rope_kernel<<<T_TOT, 256, 0, stream>>>(qkv);
    // 4) causal attention (reads qkv, writes region A)
    attn_kernel<<<dim3(32, NHEADS), 256, 0, stream>>>(qkv, attn_out);
    // 5) O-projection + residual
    gemm_kernel<2><<<dim3(16, 32), 256, 0, stream>>>(attn_out, W_attn_o, x_ffn_in,
                                                     x_input, T_TOT, 1024, 1024);
    // 6) ffn RMSNorm
    rmsnorm_kernel<<<T_TOT, 256, 0, stream>>>(x_ffn_in, ffn_w, x_ffn);
    // 7) router scores
    router_kernel<<<dim3(1024, 2), 256, 0, stream>>>(x_ffn, p_keys, f_keys,
                                                     p_idx, f_idx, p_val, f_val,
                                                     p_bias, f_bias, sc);
    // 8) expert buckets
    buckets_kernel<<<1, 1024, 0, stream>>>(p_idx, f_idx, counts, offsets, pair_p);
    // 9) MoE gate/up + silu (qkv dead; h_pairs into R1)
    moe_gateup_kernel<<<dim3(64, 32, 8), 256, 0, stream>>>(x_ffn, p_exp, f_exp,
                                                           pair_p, counts, offsets,
                                                           h_pairs);
    // 10) y (d_out) := x_ffn_in
    hipMemcpyAsync(y32, x_ffn_in, (size_t)T_TOT * DMODEL * sizeof(float),
                   hipMemcpyDeviceToDevice, stream);
    // 11) MoE down: atomic accumulate sc * (h @ Wd) into y
    moe_down_kernel<<<dim3(64, 32, 16), 256, 0, stream>>>(h_pairs, p_exp, f_exp,
                                                          pair_p, counts, offsets,
                                                          sc, y32);
    // 12) shared expert gate/up fused (hs into R1; h_pairs dead after 11)
    shared_gateup_kernel<<<dim3(32, 32), 256, 0, stream>>>(x_ffn, ffn_up, hs);
    // 13) shared expert down, accumulate into y
    gemm_kernel<1><<<dim3(16, 32), 256, 0, stream>>>(hs, ffn_down, y32, nullptr,
                                                     T_TOT, 1024, 2048);
}